// Round 1
// baseline (34.019 us; speedup 1.0000x reference)
//
#include <hip/hip_runtime.h>
#include <math.h>

// VectorQuantizer: B=4, T=2048, DIM=64, NUM_CODES=512
// out = [ k as float (8192) | z_q (8192*64) ]

#define NQ      8192
#define VDIM    64
#define NCODES  512
#define NSPLIT  16                    // code chunks (32 codes each)
#define CODES_PER_CHUNK (NCODES / NSPLIT)

// Kernel 1: each wave handles 64 queries (lane = query) x 32 codes.
// grid: 512 blocks x 256 threads (4 waves/block). blockIdx: [qgroup(128)][cquarter(4)]
// Partial best (norm, idx) per (chunk, query) -> workspace.
__global__ __launch_bounds__(256) void vq_partial_kernel(
    const float* __restrict__ inp,     // [NQ][VDIM]
    const float* __restrict__ table,   // [NCODES][VDIM]
    float* __restrict__ wnorm,         // [NSPLIT][NQ]
    int* __restrict__ widx)            // [NSPLIT][NQ]
{
    const int lane = threadIdx.x & 63;
    const int wave = threadIdx.x >> 6;          // 0..3
    const int bq   = blockIdx.x >> 2;           // 0..127 query group
    const int bc   = blockIdx.x & 3;            // 0..3 code quarter
    const int part = bc * 4 + wave;             // 0..15
    const int q    = bq * 64 + lane;

    int cbase = part * CODES_PER_CHUNK;
    cbase = __builtin_amdgcn_readfirstlane(cbase);  // wave-uniform -> scalar path

    // Load query vector into registers (16 x float4 per lane).
    float qv[VDIM];
    const float4* qp = reinterpret_cast<const float4*>(inp + (size_t)q * VDIM);
#pragma unroll
    for (int i = 0; i < 16; ++i) {
        float4 v = qp[i];
        qv[4*i+0] = v.x; qv[4*i+1] = v.y; qv[4*i+2] = v.z; qv[4*i+3] = v.w;
    }

    float best = INFINITY;
    int   bidx = 0;

    for (int c = 0; c < CODES_PER_CHUNK; ++c) {
        const float4* crow = reinterpret_cast<const float4*>(table + (size_t)(cbase + c) * VDIM);
        // 8 accumulators, element d goes to acc[d & 7]; combine with a fixed tree
        // (mirrors numpy's 8-way-unrolled pairwise reduction order closely).
        float acc[8];
#pragma unroll
        for (int j = 0; j < 8; ++j) acc[j] = 0.0f;
#pragma unroll
        for (int i = 0; i < 16; ++i) {
            float4 cv = crow[i];
            float d0 = qv[4*i+0] - cv.x;
            float d1 = qv[4*i+1] - cv.y;
            float d2 = qv[4*i+2] - cv.z;
            float d3 = qv[4*i+3] - cv.w;
            acc[(4*i+0) & 7] = __builtin_fmaf(d0, d0, acc[(4*i+0) & 7]);
            acc[(4*i+1) & 7] = __builtin_fmaf(d1, d1, acc[(4*i+1) & 7]);
            acc[(4*i+2) & 7] = __builtin_fmaf(d2, d2, acc[(4*i+2) & 7]);
            acc[(4*i+3) & 7] = __builtin_fmaf(d3, d3, acc[(4*i+3) & 7]);
        }
        float s = ((acc[0] + acc[1]) + (acc[2] + acc[3]))
                + ((acc[4] + acc[5]) + (acc[6] + acc[7]));
        float n = sqrtf(s);   // IEEE sqrt: matches ref's norm-space comparison/ties
        if (n < best) {       // strict <, ascending c -> first-min-index tie-break
            best = n;
            bidx = cbase + c;
        }
    }

    wnorm[(size_t)part * NQ + q] = best;
    widx [(size_t)part * NQ + q] = bidx;
}

// Kernel 2: reduce 16 partials per query (ascending -> lowest-index tie-break),
// write k (as float) and gather z_q coalesced. grid: NQ*64/256 blocks.
__global__ __launch_bounds__(256) void vq_finalize_kernel(
    const float* __restrict__ table,
    const float* __restrict__ wnorm,
    const int* __restrict__ widx,
    float* __restrict__ out)
{
    const int gid = blockIdx.x * 256 + threadIdx.x;   // 0 .. NQ*64
    const int q = gid >> 6;
    const int d = gid & 63;

    float best = INFINITY;
    int   bidx = 0;
#pragma unroll
    for (int p = 0; p < NSPLIT; ++p) {
        float n = wnorm[(size_t)p * NQ + q];
        int   i = widx [(size_t)p * NQ + q];
        if (n < best) { best = n; bidx = i; }   // ascending code ranges
    }

    out[NQ + (size_t)q * VDIM + d] = table[(size_t)bidx * VDIM + d];
    if (d == 0) out[q] = (float)bidx;
}

extern "C" void kernel_launch(void* const* d_in, const int* in_sizes, int n_in,
                              void* d_out, int out_size, void* d_ws, size_t ws_size,
                              hipStream_t stream) {
    const float* inp   = (const float*)d_in[0];   // [4,2048,64] fp32
    const float* table = (const float*)d_in[1];   // [512,64]    fp32
    float* out = (float*)d_out;

    float* wnorm = (float*)d_ws;                       // NSPLIT*NQ floats
    int*   widx  = (int*)(wnorm + (size_t)NSPLIT * NQ); // NSPLIT*NQ ints  (total 1 MB)

    // Kernel 1: 128 qgroups x 4 code-quarters = 512 blocks x 256 threads
    vq_partial_kernel<<<dim3(128 * 4), dim3(256), 0, stream>>>(inp, table, wnorm, widx);

    // Kernel 2: NQ*64 threads
    vq_finalize_kernel<<<dim3((NQ * VDIM) / 256), dim3(256), 0, stream>>>(table, wnorm, widx, out);
}